// Round 8
// baseline (61.341 us; speedup 1.0000x reference)
//
#include <hip/hip_runtime.h>

// FFM pairwise cross-term layer.
// out[b, p, d] = W[jj[p], adj[b, ii[p]], d] * W[ii[p], adj[b, jj[p]], d]
// B=8192, F=23, P=253, D=32, VOCAB=190001, fp32.
//
// R8 A/B vs R7: identical structure (LDS-staged pair stripes, TB=2048),
// single variable: plain store -> __builtin_nontemporal_store.
// Store-BW ledger: R4(NT,1KB)=54.3, R6(plain,256B)=54.0, R7(plain,256B,
// -78MB reads)=53.3 -> all ~5 TB/s effective store BW. This tests whether
// the write-back eviction path (vs NT no-allocate drain) matters once reads
// are LDS-served. If unchanged -> structural roofline at ~87% of copy BW.

#define NF 23
#define NP 253
#define VOCAB 190001
#define G 2                // pairs per block
#define NGRP 127           // ceil(253/2): 126 full groups + 1 single
#define TB 2048            // batch elems per block
#define NTILE (8192 / TB)  // 4
#define ROWF4 9            // padded LDS row stride in float4 (144 B)

typedef float f32x4 __attribute__((ext_vector_type(4)));

__global__ __launch_bounds__(512) void ffm_cross_kernel(
    const int* __restrict__ x,
    const int* __restrict__ offs,
    const float* __restrict__ W,
    float* __restrict__ out)
{
    // 4 stripes x 100 rows x 9 f4 x 16 B = 57.6 KB
    __shared__ f32x4 stripes[G * 2 * 100 * ROWF4];
    __shared__ unsigned char vA[TB][G];  // x[b, i] for pair pl
    __shared__ unsigned char vB[TB][G];  // x[b, j] for pair pl

    const int bid  = blockIdx.x;
    const int g    = bid / NTILE;       // group id (consecutive bids share g)
    const int tile = bid % NTILE;
    const int p0   = g * G;
    const int np   = (NP - p0 < G) ? (NP - p0) : G;  // 2, or 1 for last group
    const int b0   = tile * TB;
    const int tid  = threadIdx.x;

    // decode pairs (uniform across block -> scalar ops)
    int fi[G], fj[G];
    size_t sbase[2 * G];  // global f4 base of each stripe
    #pragma unroll
    for (int pl = 0; pl < G; ++pl) {
        int p = p0 + ((pl < np) ? pl : 0);
        int rem = p, i = 0;
        while (rem >= NF - 1 - i) { rem -= NF - 1 - i; ++i; }
        int j = i + 1 + rem;
        fi[pl] = i; fj[pl] = j;
        int offi = offs[i], offj = offs[j];
        sbase[pl * 2]     = ((size_t)j * VOCAB + (size_t)offi) * 8;  // A: W[j, offs_i+v]
        sbase[pl * 2 + 1] = ((size_t)i * VOCAB + (size_t)offj) * 8;  // B: W[i, offs_j+v]
    }

    const f32x4* __restrict__ W4 = reinterpret_cast<const f32x4*>(W);

    // ---- stage stripes: np*2 stripes x 800 f4, contiguous global reads ----
    for (int u = tid; u < np * 2 * 800; u += 512) {
        int s = u / 800;
        int t = u - s * 800;           // f4 within stripe
        int row = t >> 3, d4 = t & 7;
        stripes[(s * 100 + row) * ROWF4 + d4] = W4[sbase[s] + t];
    }

    // ---- stage per-batch raw indices ----
    for (int bl = tid; bl < TB; bl += 512) {
        const int* xr = x + (size_t)(b0 + bl) * NF;
        #pragma unroll
        for (int pl = 0; pl < G; ++pl) {
            if (pl < np) {
                vA[bl][pl] = (unsigned char)xr[fi[pl]];
                vB[bl][pl] = (unsigned char)xr[fj[pl]];
            }
        }
    }
    __syncthreads();

    f32x4* __restrict__ O4 = reinterpret_cast<f32x4*>(out);

    // ---- compute + NT stores: e = (bl*G + pl)*8 + d4 ----
    #pragma unroll 4
    for (int it = 0; it < (TB * G * 8) / 512; ++it) {  // 64 iterations
        int e  = tid + it * 512;
        int d4 = e & 7;
        int pl = (e >> 3) & (G - 1);
        int bl = e >> 4;
        if (pl < np) {
            int s0 = pl * 2;
            f32x4 a = stripes[((s0    ) * 100 + vA[bl][pl]) * ROWF4 + d4];
            f32x4 c = stripes[((s0 + 1) * 100 + vB[bl][pl]) * ROWF4 + d4];
            f32x4 r = a * c;
            size_t o = (size_t)(b0 + bl) * (NP * 8) + (size_t)(p0 + pl) * 8 + d4;
            __builtin_nontemporal_store(r, &O4[o]);
        }
    }
}

extern "C" void kernel_launch(void* const* d_in, const int* in_sizes, int n_in,
                              void* d_out, int out_size, void* d_ws, size_t ws_size,
                              hipStream_t stream)
{
    const int*   x    = (const int*)d_in[0];    // [8192, 23] int32
    const int*   offs = (const int*)d_in[1];    // [23] int32
    const float* W    = (const float*)d_in[2];  // [23, 190001, 32] fp32
    float*       out  = (float*)d_out;          // [8192, 253, 32] fp32

    ffm_cross_kernel<<<NGRP * NTILE, 512, 0, stream>>>(x, offs, W, out);
}

// Round 9
// 50.417 us; speedup vs baseline: 1.2167x; 1.2167x over previous
//
#include <hip/hip_runtime.h>

// FFM pairwise cross-term layer.
// out[b, p, d] = W[jj[p], adj[b, ii[p]], d] * W[ii[p], adj[b, jj[p]], d]
// B=8192, F=23, P=253, D=32, VOCAB=190001, fp32.
//
// R9 A/B vs R7: single variable — 512 -> 1024 threads/block.
// LDS unchanged (65.6 KB -> 2 blocks/CU) so waves/CU doubles 16 -> 32 (HW
// max), testing whether latency hiding / outstanding-store concurrency is
// the residual limiter. Store ledger: plain+LDS = 5.0 TB/s (R7 53.3us),
// NT = 4.3-4.9 TB/s (R4/R8), floor at copy-ceiling = ~43us.

#define NF 23
#define NP 253
#define VOCAB 190001
#define G 2                // pairs per block
#define NGRP 127           // ceil(253/2): 126 full groups + 1 single
#define TB 2048            // batch elems per block
#define NTILE (8192 / TB)  // 4
#define ROWF4 9            // padded LDS row stride in float4 (144 B)
#define NT_THREADS 1024

typedef float f32x4 __attribute__((ext_vector_type(4)));

__global__ __launch_bounds__(NT_THREADS) void ffm_cross_kernel(
    const int* __restrict__ x,
    const int* __restrict__ offs,
    const float* __restrict__ W,
    float* __restrict__ out)
{
    // 4 stripes x 100 rows x 9 f4 x 16 B = 57.6 KB
    __shared__ f32x4 stripes[G * 2 * 100 * ROWF4];
    __shared__ unsigned char vA[TB][G];  // x[b, i] for pair pl
    __shared__ unsigned char vB[TB][G];  // x[b, j] for pair pl

    const int bid  = blockIdx.x;
    const int g    = bid / NTILE;       // group id (consecutive bids share g)
    const int tile = bid % NTILE;
    const int p0   = g * G;
    const int np   = (NP - p0 < G) ? (NP - p0) : G;  // 2, or 1 for last group
    const int b0   = tile * TB;
    const int tid  = threadIdx.x;

    // decode pairs (uniform across block -> scalar ops)
    int fi[G], fj[G];
    size_t sbase[2 * G];  // global f4 base of each stripe
    #pragma unroll
    for (int pl = 0; pl < G; ++pl) {
        int p = p0 + ((pl < np) ? pl : 0);
        int rem = p, i = 0;
        while (rem >= NF - 1 - i) { rem -= NF - 1 - i; ++i; }
        int j = i + 1 + rem;
        fi[pl] = i; fj[pl] = j;
        int offi = offs[i], offj = offs[j];
        sbase[pl * 2]     = ((size_t)j * VOCAB + (size_t)offi) * 8;  // A: W[j, offs_i+v]
        sbase[pl * 2 + 1] = ((size_t)i * VOCAB + (size_t)offj) * 8;  // B: W[i, offs_j+v]
    }

    const f32x4* __restrict__ W4 = reinterpret_cast<const f32x4*>(W);

    // ---- stage stripes: np*2 stripes x 800 f4, contiguous global reads ----
    for (int u = tid; u < np * 2 * 800; u += NT_THREADS) {
        int s = u / 800;
        int t = u - s * 800;           // f4 within stripe
        int row = t >> 3, d4 = t & 7;
        stripes[(s * 100 + row) * ROWF4 + d4] = W4[sbase[s] + t];
    }

    // ---- stage per-batch raw indices ----
    for (int bl = tid; bl < TB; bl += NT_THREADS) {
        const int* xr = x + (size_t)(b0 + bl) * NF;
        #pragma unroll
        for (int pl = 0; pl < G; ++pl) {
            if (pl < np) {
                vA[bl][pl] = (unsigned char)xr[fi[pl]];
                vB[bl][pl] = (unsigned char)xr[fj[pl]];
            }
        }
    }
    __syncthreads();

    f32x4* __restrict__ O4 = reinterpret_cast<f32x4*>(out);

    // ---- compute + plain stores: e = (bl*G + pl)*8 + d4 ----
    #pragma unroll 4
    for (int it = 0; it < (TB * G * 8) / NT_THREADS; ++it) {  // 32 iterations
        int e  = tid + it * NT_THREADS;
        int d4 = e & 7;
        int pl = (e >> 3) & (G - 1);
        int bl = e >> 4;
        if (pl < np) {
            int s0 = pl * 2;
            f32x4 a = stripes[((s0    ) * 100 + vA[bl][pl]) * ROWF4 + d4];
            f32x4 c = stripes[((s0 + 1) * 100 + vB[bl][pl]) * ROWF4 + d4];
            size_t o = (size_t)(b0 + bl) * (NP * 8) + (size_t)(p0 + pl) * 8 + d4;
            O4[o] = a * c;
        }
    }
}

extern "C" void kernel_launch(void* const* d_in, const int* in_sizes, int n_in,
                              void* d_out, int out_size, void* d_ws, size_t ws_size,
                              hipStream_t stream)
{
    const int*   x    = (const int*)d_in[0];    // [8192, 23] int32
    const int*   offs = (const int*)d_in[1];    // [23] int32
    const float* W    = (const float*)d_in[2];  // [23, 190001, 32] fp32
    float*       out  = (float*)d_out;          // [8192, 253, 32] fp32

    ffm_cross_kernel<<<NGRP * NTILE, NT_THREADS, 0, stream>>>(x, offs, W, out);
}